// Round 1
// baseline (562.844 us; speedup 1.0000x reference)
//
#include <hip/hip_runtime.h>
#include <stdint.h>

typedef short bf16x8 __attribute__((ext_vector_type(8)));
typedef short bf16x4 __attribute__((ext_vector_type(4)));
typedef float f32x4  __attribute__((ext_vector_type(4)));

__device__ __forceinline__ short f2bf(float f) {
    uint32_t u = __builtin_bit_cast(uint32_t, f);
    u += 0x7FFFu + ((u >> 16) & 1u);   // round-to-nearest-even
    return (short)(u >> 16);
}

// Wt[t][oc][ic] = bf16(W[t][ic][oc]);  t = dy*3+dx in [0,9), oc in [0,256), ic in [0,64)
__global__ void wt_kernel(const float* __restrict__ W, short* __restrict__ Wt) {
    int idx = blockIdx.x * 256 + threadIdx.x;
    if (idx >= 9 * 256 * 64) return;
    int t   = idx >> 14;       // / 16384
    int rem = idx & 16383;
    int oc  = rem >> 6;
    int ic  = rem & 63;
    Wt[idx] = f2bf(W[(t * 64 + ic) * 256 + oc]);
}

// Implicit-GEMM conv3x3 + bias + pixel_shuffle(R=2), bf16 MFMA.
// Block: 512 threads = 8 waves (2 M x 4 N). Tile: M=128 (2 h-rows x 64 w), N=256 oc, K=576.
__global__ __launch_bounds__(512) void conv_ps_kernel(
    const float* __restrict__ x, const short* __restrict__ Wt,
    const float* __restrict__ bias, float* __restrict__ out)
{
    // LDS: A = [2 h-rows][66 w-pos][64 ic + 8 pad] bf16 ; B = [256 oc][64 ic + 8 pad] bf16
    __shared__ short As[2 * 66 * 72];   // 19,008 B
    __shared__ short Bs[256 * 72];      // 36,864 B

    const int tid   = threadIdx.x;
    const int lane  = tid & 63;
    const int wv    = tid >> 6;
    const int wm    = wv >> 2;          // 0..1 : which 64-row half
    const int wn    = wv & 3;           // 0..3 : which 64-oc block
    const int row_l = lane & 15;
    const int grp   = lane >> 4;

    const int bid = blockIdx.x;
    const int wt  = bid % 3;
    const int hp  = (bid / 3) % 96;
    const int n   = bid / (3 * 96);
    const int h0  = hp * 2;
    const int w0  = wt * 64;

    f32x4 acc[4][4];
    #pragma unroll
    for (int i = 0; i < 4; ++i)
        #pragma unroll
        for (int j = 0; j < 4; ++j)
            acc[i][j] = (f32x4)0.0f;

    for (int dy = 0; dy < 3; ++dy) {
        for (int dx = 0; dx < 3; ++dx) {
            __syncthreads();   // previous compute done before overwriting LDS
            if (dx == 0) {
                // stage A: x[n, h0+dy-1 + r, w0-1 .. w0+64, 0:64] -> bf16
                for (int i = tid; i < 2112; i += 512) {      // 2*66*16 float4 chunks
                    int r   = (i >= 1056);
                    int j   = i - r * 1056;
                    int pos = j >> 4;
                    int c4  = (j & 15) << 2;
                    int hy  = h0 + dy - 1 + r;
                    int wg  = w0 - 1 + pos;
                    f32x4 v = (f32x4)0.0f;
                    if ((unsigned)hy < 192u && (unsigned)wg < 192u) {
                        v = *(const f32x4*)(x + (((size_t)n * 192 + hy) * 192 + wg) * 64 + c4);
                    }
                    bf16x4 s;
                    s[0] = f2bf(v[0]); s[1] = f2bf(v[1]); s[2] = f2bf(v[2]); s[3] = f2bf(v[3]);
                    *(bf16x4*)&As[(r * 66 + pos) * 72 + c4] = s;
                }
            }
            {   // stage B: Wt[dy*3+dx][oc][ic] -> Bs[oc][ic]
                const short* src = Wt + (dy * 3 + dx) * 16384;
                for (int i = tid; i < 2048; i += 512) {      // 16B chunks
                    int oc = i >> 3;
                    int c8 = (i & 7) << 3;
                    bf16x8 v = *(const bf16x8*)(src + oc * 64 + c8);
                    *(bf16x8*)&Bs[oc * 72 + c8] = v;
                }
            }
            __syncthreads();

            #pragma unroll
            for (int ks = 0; ks < 2; ++ks) {
                bf16x8 af[4], bf[4];
                #pragma unroll
                for (int mt = 0; mt < 4; ++mt)
                    af[mt] = *(const bf16x8*)&As[(wm * 66 + mt * 16 + row_l + dx) * 72 + ks * 32 + grp * 8];
                #pragma unroll
                for (int nt = 0; nt < 4; ++nt)
                    bf[nt] = *(const bf16x8*)&Bs[(wn * 64 + nt * 16 + row_l) * 72 + ks * 32 + grp * 8];
                #pragma unroll
                for (int mt = 0; mt < 4; ++mt)
                    #pragma unroll
                    for (int nt = 0; nt < 4; ++nt)
                        acc[mt][nt] = __builtin_amdgcn_mfma_f32_16x16x32_bf16(
                            af[mt], bf[nt], acc[mt][nt], 0, 0, 0);
            }
        }
    }

    // Epilogue: bias + pixel shuffle. D frag: row=(lane>>4)*4+j, col=lane&15.
    // oc = wn*64 + nt*16 + row_l ; nt*16 = 0 mod 4 -> q,p,kbase are lane constants.
    const int ocl  = wn * 64 + row_l;
    const int q    = ocl & 1;
    const int p    = (ocl >> 1) & 1;
    const int kb   = ocl >> 2;
    const int h    = h0 + wm;
    const long rowbase = ((long)(n * 384 + 2 * h + q)) * 384;

    #pragma unroll
    for (int nt = 0; nt < 4; ++nt) {
        float bv = bias[ocl + nt * 16];
        int k = kb + nt * 4;
        #pragma unroll
        for (int mt = 0; mt < 4; ++mt) {
            #pragma unroll
            for (int j = 0; j < 4; ++j) {
                int w = w0 + mt * 16 + grp * 4 + j;
                long idx = (rowbase + (2 * w + p)) * 64 + k;
                out[idx] = acc[mt][nt][j] + bv;
            }
        }
    }
}

extern "C" void kernel_launch(void* const* d_in, const int* in_sizes, int n_in,
                              void* d_out, int out_size, void* d_ws, size_t ws_size,
                              hipStream_t stream) {
    const float* x = (const float*)d_in[0];
    const float* W = (const float*)d_in[1];
    const float* b = (const float*)d_in[2];
    float* out = (float*)d_out;
    short* Wt  = (short*)d_ws;   // 9*256*64 bf16 = 294,912 B

    hipLaunchKernelGGL(wt_kernel, dim3(576), dim3(256), 0, stream, W, Wt);
    hipLaunchKernelGGL(conv_ps_kernel, dim3(16 * 96 * 3), dim3(512), 0, stream, x, Wt, b, out);
}